// Round 11
// baseline (1108.019 us; speedup 1.0000x reference)
//
#include <hip/hip_runtime.h>
#include <math.h>

#define N_NODES 50000
#define N_EDGES 500000

// ws layout (float element offsets)
#define OFF_QN   0
#define OFF_KN   6400000
#define OFF_VN   12800000
#define OFF_AGG  19200000   // [N,128] attention output, already softmax-normalized
#define OFF_CNT  25600000   // 50'000 ints: counts -> scatter cursor
#define OFF_OFFS 25650000   // 50'001 ints: CSR row offsets
#define OFF_SORT 25700004   // 500'000 ints: edge ids sorted by target
#define OFF_UPD  OFF_VN     // vn dead after edge kernel
#define OFF_FF1  OFF_QN     // qn+kn dead after edge kernel ([N,256])

__global__ void k_zero_int(int* __restrict__ p, int n) {
    int i = blockIdx.x * blockDim.x + threadIdx.x;
    if (i < n) p[i] = 0;
}

// ---------------- counting sort: histogram / scan / scatter ----------------
__global__ void k_hist(const int* __restrict__ ei, int* __restrict__ cnt) {
    int i = blockIdx.x * blockDim.x + threadIdx.x;
    int st = gridDim.x * blockDim.x;
    for (int e = i; e < N_EDGES; e += st) atomicAdd(&cnt[ei[N_EDGES + e]], 1);
}

__global__ __launch_bounds__(1024) void k_scan(int* __restrict__ cnt, int* __restrict__ offs) {
    __shared__ int s[1024];
    const int t = threadIdx.x;
    const int CH = (N_NODES + 1023) / 1024;  // 49
    int lo = t * CH;
    int hi = lo + CH; if (hi > N_NODES) hi = N_NODES;
    int lsum = 0;
    for (int i = lo; i < hi; ++i) lsum += cnt[i];
    s[t] = lsum;
    __syncthreads();
    for (int d = 1; d < 1024; d <<= 1) {
        int v = (t >= d) ? s[t - d] : 0;
        __syncthreads();
        s[t] += v;
        __syncthreads();
    }
    int run = s[t] - lsum;  // exclusive prefix of this thread's chunk
    for (int i = lo; i < hi; ++i) {
        int c = cnt[i];
        offs[i] = run;
        cnt[i] = run;       // cursor copy for scatter (read c first -> safe in-place)
        run += c;
    }
    if (t == 1023) offs[N_NODES] = s[1023];
}

__global__ void k_scatter(const int* __restrict__ ei, int* __restrict__ cur, int* __restrict__ srt) {
    int i = blockIdx.x * blockDim.x + threadIdx.x;
    int st = gridDim.x * blockDim.x;
    for (int e = i; e < N_EDGES; e += st) {
        int t = ei[N_EDGES + e];
        int p = atomicAdd(&cur[t], 1);
        srt[p] = e;
    }
}

#define FMA16()                                                                 \
    {                                                                           \
        float4 b = *(float4*)&Bs[kk][tx << 2];                                  \
        float a0 = As[ty4 + 0][kk], a1 = As[ty4 + 1][kk];                       \
        float a2 = As[ty4 + 2][kk], a3 = As[ty4 + 3][kk];                       \
        acc[0][0] = fmaf(a0, b.x, acc[0][0]); acc[0][1] = fmaf(a0, b.y, acc[0][1]); \
        acc[0][2] = fmaf(a0, b.z, acc[0][2]); acc[0][3] = fmaf(a0, b.w, acc[0][3]); \
        acc[1][0] = fmaf(a1, b.x, acc[1][0]); acc[1][1] = fmaf(a1, b.y, acc[1][1]); \
        acc[1][2] = fmaf(a1, b.z, acc[1][2]); acc[1][3] = fmaf(a1, b.w, acc[1][3]); \
        acc[2][0] = fmaf(a2, b.x, acc[2][0]); acc[2][1] = fmaf(a2, b.y, acc[2][1]); \
        acc[2][2] = fmaf(a2, b.z, acc[2][2]); acc[2][3] = fmaf(a2, b.w, acc[2][3]); \
        acc[3][0] = fmaf(a3, b.x, acc[3][0]); acc[3][1] = fmaf(a3, b.y, acc[3][1]); \
        acc[3][2] = fmaf(a3, b.z, acc[3][2]); acc[3][3] = fmaf(a3, b.w, acc[3][3]); \
    }

// ---------------- per-node q / k_node / v_node ----------------
__global__ __launch_bounds__(256) void k_node_qkv(
    const float* __restrict__ ns, const float* __restrict__ nt,
    const float* __restrict__ Wq, const float* __restrict__ bq,
    const float* __restrict__ Wk, const float* __restrict__ bk,
    const float* __restrict__ Wv, const float* __restrict__ bv,
    float* __restrict__ ws)
{
    const int which = blockIdx.y;
    const float* W    = which == 0 ? Wq : (which == 1 ? Wk : Wv);
    const float* bias = which == 0 ? bq : (which == 1 ? bk : bv);
    float* out = ws + (which == 0 ? OFF_QN : (which == 1 ? OFF_KN : OFF_VN));

    __shared__ float As[32][33];
    __shared__ float Bs[32][128];
    const int tid = threadIdx.x;
    const int tx = tid & 31, ty = tid >> 5, ty4 = ty << 2;
    const int row0 = blockIdx.x * 32;
    float acc[4][4] = {};

    for (int k0 = 0; k0 < 160; k0 += 32) {
        #pragma unroll
        for (int l = 0; l < 4; l++) {
            int idx = tid + l * 256;
            int r = idx >> 5, c = idx & 31;
            int gr = row0 + r, gc = k0 + c;
            float v = 0.f;
            if (gr < N_NODES) v = (gc < 128) ? ns[gr * 128 + gc] : nt[gr * 32 + gc - 128];
            As[r][c] = v;
        }
        #pragma unroll
        for (int l = 0; l < 4; l++) {
            int idx = tid + l * 256;
            int r = idx >> 5, c = (idx & 31) << 2;
            *(float4*)&Bs[r][c] = *(const float4*)&W[(k0 + r) * 128 + c];
        }
        __syncthreads();
        #pragma unroll
        for (int kk = 0; kk < 32; kk++) FMA16();
        __syncthreads();
    }
    float4 bb = *(const float4*)&bias[tx << 2];
    #pragma unroll
    for (int r = 0; r < 4; r++) {
        int gr = row0 + ty4 + r;
        if (gr < N_NODES) {
            float4 o = {acc[r][0] + bb.x, acc[r][1] + bb.y, acc[r][2] + bb.z, acc[r][3] + bb.w};
            *(float4*)&out[gr * 128 + (tx << 2)] = o;
        }
    }
}

// ---------------- CSR edge attention: 1 wave per target node, no atomics ----------------
// lane owns dims 2*lane, 2*lane+1; head h = lane>>3 (8 lanes per head).
// agg[n] = (sum_e ex*v_e) / max(sum_e ex, 1e-9) fused here; den array eliminated.
__global__ __launch_bounds__(256) void k_edge_csr(
    const int* __restrict__ ei, const float* __restrict__ ee,
    const float* WkE, const float* WvE,
    const int* __restrict__ offs, const int* __restrict__ srt,
    float* __restrict__ ws)
{
    const float* qn = ws + OFF_QN;
    const float* kn = ws + OFF_KN;
    const float* vn = ws + OFF_VN;
    float* agg = ws + OFF_AGG;

    const int lane = threadIdx.x & 63;
    const int w = (blockIdx.x * blockDim.x + threadIdx.x) >> 6;
    if (w >= N_NODES) return;

    // Weight cache: volatile loads cannot be rematerialized -> values must stay
    // in VGPRs across the edge loop (round-9 profile showed VGPR=72, i.e. the
    // compiler was re-loading these 64x per edge).
    float wk[32][2], wv[32][2];
    {
        volatile const float* vk = WkE;
        volatile const float* vv = WvE;
        #pragma unroll
        for (int j = 0; j < 32; j++) {
            wk[j][0] = vk[j * 128 + 2 * lane];
            wk[j][1] = vk[j * 128 + 2 * lane + 1];
            wv[j][0] = vv[j * 128 + 2 * lane];
            wv[j][1] = vv[j * 128 + 2 * lane + 1];
        }
    }

    const int wu = __builtin_amdgcn_readfirstlane(w);
    const int beg = offs[wu];
    const int end = offs[wu + 1];
    float2 qv = *(const float2*)&qn[w * 128 + 2 * lane];

    float a1 = 0.f, a2 = 0.f, ad = 0.f;
    for (int i = beg; i < end; ++i) {
        int iu = __builtin_amdgcn_readfirstlane(i);
        int eid = srt[iu];          // uniform -> scalar load
        int src = ei[eid];          // uniform -> scalar load
        float2 kv2 = *(const float2*)&kn[src * 128 + 2 * lane];
        float2 vv2 = *(const float2*)&vn[src * 128 + 2 * lane];
        float k1 = kv2.x, k2 = kv2.y, v1 = vv2.x, v2 = vv2.y;
        #pragma unroll
        for (int j = 0; j < 32; j++) {
            float c = ee[eid * 32 + j];  // uniform -> scalar load
            k1 = fmaf(c, wk[j][0], k1);
            k2 = fmaf(c, wk[j][1], k2);
            v1 = fmaf(c, wv[j][0], v1);
            v2 = fmaf(c, wv[j][1], v2);
        }
        float p = qv.x * k1 + qv.y * k2;
        p += __shfl_xor(p, 1);
        p += __shfl_xor(p, 2);
        p += __shfl_xor(p, 4);               // p uniform within 8-lane head group
        float ex = expf(p * 0.25f);          // scale 1/sqrt(16); |logit| << 1, no max needed
        ad += ex;
        a1 = fmaf(ex, v1, a1);
        a2 = fmaf(ex, v2, a2);
    }
    float inv = 1.0f / fmaxf(ad, 1e-9f);
    float2 o = {a1 * inv, a2 * inv};
    *(float2*)&agg[w * 128 + 2 * lane] = o;
}

// ---------------- agg @ Wo + bo + ns -> LN1 -> upd ----------------
__global__ __launch_bounds__(256) void k_out_ln1(
    const float* __restrict__ ns,
    const float* __restrict__ Wo, const float* __restrict__ bo,
    const float* __restrict__ g1, const float* __restrict__ be1,
    float* __restrict__ ws)
{
    const float* agg = ws + OFF_AGG;
    float* upd = ws + OFF_UPD;
    __shared__ float As[32][33];
    __shared__ float Bs[32][128];
    const int tid = threadIdx.x;
    const int tx = tid & 31, ty = tid >> 5, ty4 = ty << 2;
    const int row0 = blockIdx.x * 32;
    float acc[4][4] = {};

    for (int k0 = 0; k0 < 128; k0 += 32) {
        #pragma unroll
        for (int l = 0; l < 4; l++) {
            int idx = tid + l * 256;
            int r = idx >> 5, c = idx & 31;
            int gr = row0 + r, gc = k0 + c;
            As[r][c] = (gr < N_NODES) ? agg[gr * 128 + gc] : 0.f;
        }
        #pragma unroll
        for (int l = 0; l < 4; l++) {
            int idx = tid + l * 256;
            int r = idx >> 5, c = (idx & 31) << 2;
            *(float4*)&Bs[r][c] = *(const float4*)&Wo[(k0 + r) * 128 + c];
        }
        __syncthreads();
        #pragma unroll
        for (int kk = 0; kk < 32; kk++) FMA16();
        __syncthreads();
    }
    float4 bo4 = *(const float4*)&bo[tx << 2];
    float4 g4  = *(const float4*)&g1[tx << 2];
    float4 b4  = *(const float4*)&be1[tx << 2];
    #pragma unroll
    for (int r = 0; r < 4; r++) {
        int gr = row0 + ty4 + r;
        bool valid = gr < N_NODES;
        float4 t = {0.f, 0.f, 0.f, 0.f};
        if (valid) {
            float4 nsv = *(const float4*)&ns[gr * 128 + (tx << 2)];
            t.x = acc[r][0] + bo4.x + nsv.x;
            t.y = acc[r][1] + bo4.y + nsv.y;
            t.z = acc[r][2] + bo4.z + nsv.z;
            t.w = acc[r][3] + bo4.w + nsv.w;
        }
        float s = t.x + t.y + t.z + t.w;
        s += __shfl_xor(s, 1); s += __shfl_xor(s, 2); s += __shfl_xor(s, 4);
        s += __shfl_xor(s, 8); s += __shfl_xor(s, 16);
        float mu = s * 0.0078125f;
        float dx = t.x - mu, dy = t.y - mu, dz = t.z - mu, dw = t.w - mu;
        float sq = dx * dx + dy * dy + dz * dz + dw * dw;
        sq += __shfl_xor(sq, 1); sq += __shfl_xor(sq, 2); sq += __shfl_xor(sq, 4);
        sq += __shfl_xor(sq, 8); sq += __shfl_xor(sq, 16);
        float rs = rsqrtf(sq * 0.0078125f + 1e-5f);
        if (valid) {
            float4 o;
            o.x = dx * rs * g4.x + b4.x;
            o.y = dy * rs * g4.y + b4.y;
            o.z = dz * rs * g4.z + b4.z;
            o.w = dw * rs * g4.w + b4.w;
            *(float4*)&upd[gr * 128 + (tx << 2)] = o;
        }
    }
}

// ---------------- upd @ W1 + bf1 -> gelu -> ff1 ----------------
__global__ __launch_bounds__(256) void k_ffn1(
    const float* __restrict__ W1, const float* __restrict__ bf1,
    float* __restrict__ ws)
{
    const float* upd = ws + OFF_UPD;
    float* ff1 = ws + OFF_FF1;
    __shared__ float As[32][33];
    __shared__ float Bs[32][128];
    const int tid = threadIdx.x;
    const int tx = tid & 31, ty = tid >> 5, ty4 = ty << 2;
    const int row0 = blockIdx.x * 32;
    const int colbase = blockIdx.y * 128;
    float acc[4][4] = {};

    for (int k0 = 0; k0 < 128; k0 += 32) {
        #pragma unroll
        for (int l = 0; l < 4; l++) {
            int idx = tid + l * 256;
            int r = idx >> 5, c = idx & 31;
            int gr = row0 + r, gc = k0 + c;
            As[r][c] = (gr < N_NODES) ? upd[gr * 128 + gc] : 0.f;
        }
        #pragma unroll
        for (int l = 0; l < 4; l++) {
            int idx = tid + l * 256;
            int r = idx >> 5, c = (idx & 31) << 2;
            *(float4*)&Bs[r][c] = *(const float4*)&W1[(k0 + r) * 256 + colbase + c];
        }
        __syncthreads();
        #pragma unroll
        for (int kk = 0; kk < 32; kk++) FMA16();
        __syncthreads();
    }
    float4 bb = *(const float4*)&bf1[colbase + (tx << 2)];
    #pragma unroll
    for (int r = 0; r < 4; r++) {
        int gr = row0 + ty4 + r;
        if (gr < N_NODES) {
            float x0 = acc[r][0] + bb.x, x1 = acc[r][1] + bb.y;
            float x2 = acc[r][2] + bb.z, x3 = acc[r][3] + bb.w;
            float4 o;
            o.x = 0.5f * x0 * (1.f + erff(x0 * 0.70710678118654752f));
            o.y = 0.5f * x1 * (1.f + erff(x1 * 0.70710678118654752f));
            o.z = 0.5f * x2 * (1.f + erff(x2 * 0.70710678118654752f));
            o.w = 0.5f * x3 * (1.f + erff(x3 * 0.70710678118654752f));
            *(float4*)&ff1[gr * 256 + colbase + (tx << 2)] = o;
        }
    }
}

// ---------------- ff1 @ W2 + bf2 + upd -> LN2 -> out ----------------
__global__ __launch_bounds__(256) void k_ffn2(
    const float* __restrict__ W2, const float* __restrict__ bf2,
    const float* __restrict__ g2, const float* __restrict__ be2,
    float* __restrict__ ws, float* __restrict__ out)
{
    const float* ff1 = ws + OFF_FF1;
    const float* upd = ws + OFF_UPD;
    __shared__ float As[32][33];
    __shared__ float Bs[32][128];
    const int tid = threadIdx.x;
    const int tx = tid & 31, ty = tid >> 5, ty4 = ty << 2;
    const int row0 = blockIdx.x * 32;
    float acc[4][4] = {};

    for (int k0 = 0; k0 < 256; k0 += 32) {
        #pragma unroll
        for (int l = 0; l < 4; l++) {
            int idx = tid + l * 256;
            int r = idx >> 5, c = idx & 31;
            int gr = row0 + r, gc = k0 + c;
            As[r][c] = (gr < N_NODES) ? ff1[gr * 256 + gc] : 0.f;
        }
        #pragma unroll
        for (int l = 0; l < 4; l++) {
            int idx = tid + l * 256;
            int r = idx >> 5, c = (idx & 31) << 2;
            *(float4*)&Bs[r][c] = *(const float4*)&W2[(k0 + r) * 128 + c];
        }
        __syncthreads();
        #pragma unroll
        for (int kk = 0; kk < 32; kk++) FMA16();
        __syncthreads();
    }
    float4 bb = *(const float4*)&bf2[tx << 2];
    float4 g4 = *(const float4*)&g2[tx << 2];
    float4 b4 = *(const float4*)&be2[tx << 2];
    #pragma unroll
    for (int r = 0; r < 4; r++) {
        int gr = row0 + ty4 + r;
        bool valid = gr < N_NODES;
        float4 t = {0.f, 0.f, 0.f, 0.f};
        if (valid) {
            float4 uv = *(const float4*)&upd[gr * 128 + (tx << 2)];
            t.x = acc[r][0] + bb.x + uv.x;
            t.y = acc[r][1] + bb.y + uv.y;
            t.z = acc[r][2] + bb.z + uv.z;
            t.w = acc[r][3] + bb.w + uv.w;
        }
        float s = t.x + t.y + t.z + t.w;
        s += __shfl_xor(s, 1); s += __shfl_xor(s, 2); s += __shfl_xor(s, 4);
        s += __shfl_xor(s, 8); s += __shfl_xor(s, 16);
        float mu = s * 0.0078125f;
        float dx = t.x - mu, dy = t.y - mu, dz = t.z - mu, dw = t.w - mu;
        float sq = dx * dx + dy * dy + dz * dz + dw * dw;
        sq += __shfl_xor(sq, 1); sq += __shfl_xor(sq, 2); sq += __shfl_xor(sq, 4);
        sq += __shfl_xor(sq, 8); sq += __shfl_xor(sq, 16);
        float rs = rsqrtf(sq * 0.0078125f + 1e-5f);
        if (valid) {
            float4 o;
            o.x = dx * rs * g4.x + b4.x;
            o.y = dy * rs * g4.y + b4.y;
            o.z = dz * rs * g4.z + b4.z;
            o.w = dw * rs * g4.w + b4.w;
            *(float4*)&out[gr * 128 + (tx << 2)] = o;
        }
    }
}

extern "C" void kernel_launch(void* const* d_in, const int* in_sizes, int n_in,
                              void* d_out, int out_size, void* d_ws, size_t ws_size,
                              hipStream_t stream)
{
    const float* ns  = (const float*)d_in[0];
    const float* nt  = (const float*)d_in[1];
    const int*   ei  = (const int*)d_in[2];
    const float* ee  = (const float*)d_in[3];
    const float* Wq  = (const float*)d_in[4];
    const float* bq  = (const float*)d_in[5];
    const float* Wk  = (const float*)d_in[6];
    const float* bk  = (const float*)d_in[7];
    const float* Wv  = (const float*)d_in[8];
    const float* bv  = (const float*)d_in[9];
    const float* Wo  = (const float*)d_in[10];
    const float* bo  = (const float*)d_in[11];
    const float* g1  = (const float*)d_in[12];
    const float* be1 = (const float*)d_in[13];
    const float* g2  = (const float*)d_in[14];
    const float* be2 = (const float*)d_in[15];
    const float* W1  = (const float*)d_in[16];
    const float* bf1 = (const float*)d_in[17];
    const float* W2  = (const float*)d_in[18];
    const float* bf2 = (const float*)d_in[19];
    float* ws  = (float*)d_ws;
    float* out = (float*)d_out;

    int* cnt  = (int*)(ws + OFF_CNT);
    int* offs = (int*)(ws + OFF_OFFS);
    int* srt  = (int*)(ws + OFF_SORT);

    const int nblk = (N_NODES + 31) / 32;

    // build CSR (counts zeroed each launch; ws is re-poisoned by harness)
    k_zero_int<<<(N_NODES + 255) / 256, 256, 0, stream>>>(cnt, N_NODES);
    k_hist<<<512, 256, 0, stream>>>(ei, cnt);
    k_scan<<<1, 1024, 0, stream>>>(cnt, offs);
    k_scatter<<<512, 256, 0, stream>>>(ei, cnt, srt);

    dim3 gq(nblk, 3);
    k_node_qkv<<<gq, 256, 0, stream>>>(ns, nt, Wq, bq, Wk, bk, Wv, bv, ws);

    // 1 wave per node: 50000 waves -> 12500 blocks of 256
    k_edge_csr<<<(N_NODES * 64 + 255) / 256, 256, 0, stream>>>(
        ei, ee, Wk + 160 * 128, Wv + 160 * 128, offs, srt, ws);

    k_out_ln1<<<nblk, 256, 0, stream>>>(ns, Wo, bo, g1, be1, ws);
    dim3 gf(nblk, 2);
    k_ffn1<<<gf, 256, 0, stream>>>(W1, bf1, ws);
    k_ffn2<<<nblk, 256, 0, stream>>>(W2, bf2, g2, be2, ws, out);
}

// Round 12
// 789.396 us; speedup vs baseline: 1.4036x; 1.4036x over previous
//
#include <hip/hip_runtime.h>
#include <math.h>

#define N_NODES 50000
#define N_EDGES 500000

// ws layout (float element offsets)
#define OFF_QN   0
#define OFF_KN   6400000
#define OFF_VN   12800000
#define OFF_AGG  19200000   // [N,128] attention output, softmax-normalized
#define OFF_CNT  25600000   // 50'000 ints: counts -> scatter cursor
#define OFF_OFFS 25650000   // 50'001 ints: CSR row offsets
#define OFF_SORT 25700004   // 500'000 ints: edge ids sorted by target
#define OFF_UPD  OFF_VN     // vn dead after edge kernel
#define OFF_FF1  OFF_QN     // qn+kn dead after edge kernel ([N,256])

__global__ void k_zero_int(int* __restrict__ p, int n) {
    int i = blockIdx.x * blockDim.x + threadIdx.x;
    if (i < n) p[i] = 0;
}

// ---------------- counting sort: histogram / scan / scatter ----------------
__global__ void k_hist(const int* __restrict__ ei, int* __restrict__ cnt) {
    int i = blockIdx.x * blockDim.x + threadIdx.x;
    int st = gridDim.x * blockDim.x;
    for (int e = i; e < N_EDGES; e += st) atomicAdd(&cnt[ei[N_EDGES + e]], 1);
}

__global__ __launch_bounds__(1024) void k_scan(int* __restrict__ cnt, int* __restrict__ offs) {
    __shared__ int s[1024];
    const int t = threadIdx.x;
    const int CH = (N_NODES + 1023) / 1024;  // 49
    int lo = t * CH;
    int hi = lo + CH; if (hi > N_NODES) hi = N_NODES;
    int lsum = 0;
    for (int i = lo; i < hi; ++i) lsum += cnt[i];
    s[t] = lsum;
    __syncthreads();
    for (int d = 1; d < 1024; d <<= 1) {
        int v = (t >= d) ? s[t - d] : 0;
        __syncthreads();
        s[t] += v;
        __syncthreads();
    }
    int run = s[t] - lsum;  // exclusive prefix of this thread's chunk
    for (int i = lo; i < hi; ++i) {
        int c = cnt[i];
        offs[i] = run;
        cnt[i] = run;       // cursor copy for scatter (read c first -> safe in-place)
        run += c;
    }
    if (t == 1023) offs[N_NODES] = s[1023];
}

__global__ void k_scatter(const int* __restrict__ ei, int* __restrict__ cur, int* __restrict__ srt) {
    int i = blockIdx.x * blockDim.x + threadIdx.x;
    int st = gridDim.x * blockDim.x;
    for (int e = i; e < N_EDGES; e += st) {
        int t = ei[N_EDGES + e];
        int p = atomicAdd(&cur[t], 1);
        srt[p] = e;
    }
}

#define FMA16()                                                                 \
    {                                                                           \
        float4 b = *(float4*)&Bs[kk][tx << 2];                                  \
        float a0 = As[ty4 + 0][kk], a1 = As[ty4 + 1][kk];                       \
        float a2 = As[ty4 + 2][kk], a3 = As[ty4 + 3][kk];                       \
        acc[0][0] = fmaf(a0, b.x, acc[0][0]); acc[0][1] = fmaf(a0, b.y, acc[0][1]); \
        acc[0][2] = fmaf(a0, b.z, acc[0][2]); acc[0][3] = fmaf(a0, b.w, acc[0][3]); \
        acc[1][0] = fmaf(a1, b.x, acc[1][0]); acc[1][1] = fmaf(a1, b.y, acc[1][1]); \
        acc[1][2] = fmaf(a1, b.z, acc[1][2]); acc[1][3] = fmaf(a1, b.w, acc[1][3]); \
        acc[2][0] = fmaf(a2, b.x, acc[2][0]); acc[2][1] = fmaf(a2, b.y, acc[2][1]); \
        acc[2][2] = fmaf(a2, b.z, acc[2][2]); acc[2][3] = fmaf(a2, b.w, acc[2][3]); \
        acc[3][0] = fmaf(a3, b.x, acc[3][0]); acc[3][1] = fmaf(a3, b.y, acc[3][1]); \
        acc[3][2] = fmaf(a3, b.z, acc[3][2]); acc[3][3] = fmaf(a3, b.w, acc[3][3]); \
    }

// ---------------- per-node q / k_node / v_node ----------------
__global__ __launch_bounds__(256) void k_node_qkv(
    const float* __restrict__ ns, const float* __restrict__ nt,
    const float* __restrict__ Wq, const float* __restrict__ bq,
    const float* __restrict__ Wk, const float* __restrict__ bk,
    const float* __restrict__ Wv, const float* __restrict__ bv,
    float* __restrict__ ws)
{
    const int which = blockIdx.y;
    const float* W    = which == 0 ? Wq : (which == 1 ? Wk : Wv);
    const float* bias = which == 0 ? bq : (which == 1 ? bk : bv);
    float* out = ws + (which == 0 ? OFF_QN : (which == 1 ? OFF_KN : OFF_VN));

    __shared__ float As[32][33];
    __shared__ float Bs[32][128];
    const int tid = threadIdx.x;
    const int tx = tid & 31, ty = tid >> 5, ty4 = ty << 2;
    const int row0 = blockIdx.x * 32;
    float acc[4][4] = {};

    for (int k0 = 0; k0 < 160; k0 += 32) {
        #pragma unroll
        for (int l = 0; l < 4; l++) {
            int idx = tid + l * 256;
            int r = idx >> 5, c = idx & 31;
            int gr = row0 + r, gc = k0 + c;
            float v = 0.f;
            if (gr < N_NODES) v = (gc < 128) ? ns[gr * 128 + gc] : nt[gr * 32 + gc - 128];
            As[r][c] = v;
        }
        #pragma unroll
        for (int l = 0; l < 4; l++) {
            int idx = tid + l * 256;
            int r = idx >> 5, c = (idx & 31) << 2;
            *(float4*)&Bs[r][c] = *(const float4*)&W[(k0 + r) * 128 + c];
        }
        __syncthreads();
        #pragma unroll
        for (int kk = 0; kk < 32; kk++) FMA16();
        __syncthreads();
    }
    float4 bb = *(const float4*)&bias[tx << 2];
    #pragma unroll
    for (int r = 0; r < 4; r++) {
        int gr = row0 + ty4 + r;
        if (gr < N_NODES) {
            float4 o = {acc[r][0] + bb.x, acc[r][1] + bb.y, acc[r][2] + bb.z, acc[r][3] + bb.w};
            *(float4*)&out[gr * 128 + (tx << 2)] = o;
        }
    }
}

// ---------------- CSR edge attention, weight-free inner loop ----------------
// Round-11 post-mortem: per-lane 128-float weight tile spilled to scratch
// (VGPR=76) -> 16 GB L2 scratch traffic. Fix: move WkE/WvE out of the edge
// loop algebraically.
//   logit = q.kn[src] + ee.qkt,  qkt[h] = WkE_h^T q_h   (per-node prologue)
//   agg   = (sum ex*vn[src] + s @ WvE) / sum ex,  s[h][j] = sum ex*ee[j]
//                                                  (per-node epilogue)
// Lane owns output dims 2*lane,2*lane+1; head h=lane>>3; ee dims j0..j0+3.
__global__ __launch_bounds__(256) void k_edge_csr(
    const int* __restrict__ ei, const float* __restrict__ ee,
    const float* __restrict__ WkE, const float* __restrict__ WvE,
    const int* __restrict__ offs, const int* __restrict__ srt,
    float* __restrict__ ws)
{
    const float* qn = ws + OFF_QN;
    const float* kn = ws + OFF_KN;
    const float* vn = ws + OFF_VN;
    float* agg = ws + OFF_AGG;

    const int lane = threadIdx.x & 63;
    const int w = (blockIdx.x * blockDim.x + threadIdx.x) >> 6;
    if (w >= N_NODES) return;

    const int h   = lane >> 3;        // head 0..7
    const int grp = lane & ~7;        // base lane of 8-lane head group
    const int j0  = (lane & 7) * 4;   // this lane's 4 edge-embedding dims

    float2 qv = *(const float2*)&qn[w * 128 + 2 * lane];

    // ---- prologue: qkt[jj] = sum_d q[h*16+d] * WkE[j0+jj][h*16+d] ----
    float qd[16];
    #pragma unroll
    for (int d = 0; d < 16; d++)
        qd[d] = __shfl((d & 1) ? qv.y : qv.x, grp + (d >> 1));
    float qkt[4] = {0.f, 0.f, 0.f, 0.f};
    #pragma unroll
    for (int jj = 0; jj < 4; jj++) {
        const float4* wrow = (const float4*)&WkE[(j0 + jj) * 128 + h * 16];
        #pragma unroll
        for (int d4 = 0; d4 < 4; d4++) {
            float4 w4 = wrow[d4];
            qkt[jj] = fmaf(qd[4 * d4 + 0], w4.x, qkt[jj]);
            qkt[jj] = fmaf(qd[4 * d4 + 1], w4.y, qkt[jj]);
            qkt[jj] = fmaf(qd[4 * d4 + 2], w4.z, qkt[jj]);
            qkt[jj] = fmaf(qd[4 * d4 + 3], w4.w, qkt[jj]);
        }
    }

    const int wu = __builtin_amdgcn_readfirstlane(w);
    const int beg = offs[wu];
    const int end = offs[wu + 1];

    // ---- edge loop: no weights, ~25 instructions ----
    float a1 = 0.f, a2 = 0.f, ad = 0.f;
    float s0 = 0.f, s1 = 0.f, s2 = 0.f, s3 = 0.f;
    for (int i = beg; i < end; ++i) {
        int iu = __builtin_amdgcn_readfirstlane(i);
        int eid = srt[iu];          // uniform -> scalar load
        int src = ei[eid];          // uniform -> scalar load
        float2 kv2 = *(const float2*)&kn[src * 128 + 2 * lane];
        float2 vv2 = *(const float2*)&vn[src * 128 + 2 * lane];
        float4 e4  = *(const float4*)&ee[eid * 32 + j0];
        float p = qv.x * kv2.x + qv.y * kv2.y
                + e4.x * qkt[0] + e4.y * qkt[1] + e4.z * qkt[2] + e4.w * qkt[3];
        p += __shfl_xor(p, 1);
        p += __shfl_xor(p, 2);
        p += __shfl_xor(p, 4);               // uniform within 8-lane head group
        float ex = expf(p * 0.25f);          // scale 1/sqrt(16); |logit| << 1
        ad += ex;
        a1 = fmaf(ex, vv2.x, a1);
        a2 = fmaf(ex, vv2.y, a2);
        s0 = fmaf(ex, e4.x, s0);
        s1 = fmaf(ex, e4.y, s1);
        s2 = fmaf(ex, e4.z, s2);
        s3 = fmaf(ex, e4.w, s3);
    }

    // ---- epilogue: extra[d] = sum_j s_all[h][j] * WvE[j][d] ----
    float x1 = 0.f, x2 = 0.f;
    #pragma unroll
    for (int j = 0; j < 32; j++) {
        float sj;
        switch (j & 3) { case 0: sj = s0; break; case 1: sj = s1; break;
                         case 2: sj = s2; break; default: sj = s3; }
        sj = __shfl(sj, grp + (j >> 2));
        float2 w2 = *(const float2*)&WvE[j * 128 + 2 * lane];
        x1 = fmaf(sj, w2.x, x1);
        x2 = fmaf(sj, w2.y, x2);
    }

    float inv = 1.0f / fmaxf(ad, 1e-9f);
    float2 o = {(a1 + x1) * inv, (a2 + x2) * inv};
    *(float2*)&agg[w * 128 + 2 * lane] = o;
}

// ---------------- agg @ Wo + bo + ns -> LN1 -> upd ----------------
__global__ __launch_bounds__(256) void k_out_ln1(
    const float* __restrict__ ns,
    const float* __restrict__ Wo, const float* __restrict__ bo,
    const float* __restrict__ g1, const float* __restrict__ be1,
    float* __restrict__ ws)
{
    const float* agg = ws + OFF_AGG;
    float* upd = ws + OFF_UPD;
    __shared__ float As[32][33];
    __shared__ float Bs[32][128];
    const int tid = threadIdx.x;
    const int tx = tid & 31, ty = tid >> 5, ty4 = ty << 2;
    const int row0 = blockIdx.x * 32;
    float acc[4][4] = {};

    for (int k0 = 0; k0 < 128; k0 += 32) {
        #pragma unroll
        for (int l = 0; l < 4; l++) {
            int idx = tid + l * 256;
            int r = idx >> 5, c = idx & 31;
            int gr = row0 + r, gc = k0 + c;
            As[r][c] = (gr < N_NODES) ? agg[gr * 128 + gc] : 0.f;
        }
        #pragma unroll
        for (int l = 0; l < 4; l++) {
            int idx = tid + l * 256;
            int r = idx >> 5, c = (idx & 31) << 2;
            *(float4*)&Bs[r][c] = *(const float4*)&Wo[(k0 + r) * 128 + c];
        }
        __syncthreads();
        #pragma unroll
        for (int kk = 0; kk < 32; kk++) FMA16();
        __syncthreads();
    }
    float4 bo4 = *(const float4*)&bo[tx << 2];
    float4 g4  = *(const float4*)&g1[tx << 2];
    float4 b4  = *(const float4*)&be1[tx << 2];
    #pragma unroll
    for (int r = 0; r < 4; r++) {
        int gr = row0 + ty4 + r;
        bool valid = gr < N_NODES;
        float4 t = {0.f, 0.f, 0.f, 0.f};
        if (valid) {
            float4 nsv = *(const float4*)&ns[gr * 128 + (tx << 2)];
            t.x = acc[r][0] + bo4.x + nsv.x;
            t.y = acc[r][1] + bo4.y + nsv.y;
            t.z = acc[r][2] + bo4.z + nsv.z;
            t.w = acc[r][3] + bo4.w + nsv.w;
        }
        float s = t.x + t.y + t.z + t.w;
        s += __shfl_xor(s, 1); s += __shfl_xor(s, 2); s += __shfl_xor(s, 4);
        s += __shfl_xor(s, 8); s += __shfl_xor(s, 16);
        float mu = s * 0.0078125f;
        float dx = t.x - mu, dy = t.y - mu, dz = t.z - mu, dw = t.w - mu;
        float sq = dx * dx + dy * dy + dz * dz + dw * dw;
        sq += __shfl_xor(sq, 1); sq += __shfl_xor(sq, 2); sq += __shfl_xor(sq, 4);
        sq += __shfl_xor(sq, 8); sq += __shfl_xor(sq, 16);
        float rs = rsqrtf(sq * 0.0078125f + 1e-5f);
        if (valid) {
            float4 o;
            o.x = dx * rs * g4.x + b4.x;
            o.y = dy * rs * g4.y + b4.y;
            o.z = dz * rs * g4.z + b4.z;
            o.w = dw * rs * g4.w + b4.w;
            *(float4*)&upd[gr * 128 + (tx << 2)] = o;
        }
    }
}

// ---------------- upd @ W1 + bf1 -> gelu -> ff1 ----------------
__global__ __launch_bounds__(256) void k_ffn1(
    const float* __restrict__ W1, const float* __restrict__ bf1,
    float* __restrict__ ws)
{
    const float* upd = ws + OFF_UPD;
    float* ff1 = ws + OFF_FF1;
    __shared__ float As[32][33];
    __shared__ float Bs[32][128];
    const int tid = threadIdx.x;
    const int tx = tid & 31, ty = tid >> 5, ty4 = ty << 2;
    const int row0 = blockIdx.x * 32;
    const int colbase = blockIdx.y * 128;
    float acc[4][4] = {};

    for (int k0 = 0; k0 < 128; k0 += 32) {
        #pragma unroll
        for (int l = 0; l < 4; l++) {
            int idx = tid + l * 256;
            int r = idx >> 5, c = idx & 31;
            int gr = row0 + r, gc = k0 + c;
            As[r][c] = (gr < N_NODES) ? upd[gr * 128 + gc] : 0.f;
        }
        #pragma unroll
        for (int l = 0; l < 4; l++) {
            int idx = tid + l * 256;
            int r = idx >> 5, c = (idx & 31) << 2;
            *(float4*)&Bs[r][c] = *(const float4*)&W1[(k0 + r) * 256 + colbase + c];
        }
        __syncthreads();
        #pragma unroll
        for (int kk = 0; kk < 32; kk++) FMA16();
        __syncthreads();
    }
    float4 bb = *(const float4*)&bf1[colbase + (tx << 2)];
    #pragma unroll
    for (int r = 0; r < 4; r++) {
        int gr = row0 + ty4 + r;
        if (gr < N_NODES) {
            float x0 = acc[r][0] + bb.x, x1 = acc[r][1] + bb.y;
            float x2 = acc[r][2] + bb.z, x3 = acc[r][3] + bb.w;
            float4 o;
            o.x = 0.5f * x0 * (1.f + erff(x0 * 0.70710678118654752f));
            o.y = 0.5f * x1 * (1.f + erff(x1 * 0.70710678118654752f));
            o.z = 0.5f * x2 * (1.f + erff(x2 * 0.70710678118654752f));
            o.w = 0.5f * x3 * (1.f + erff(x3 * 0.70710678118654752f));
            *(float4*)&ff1[gr * 256 + colbase + (tx << 2)] = o;
        }
    }
}

// ---------------- ff1 @ W2 + bf2 + upd -> LN2 -> out ----------------
__global__ __launch_bounds__(256) void k_ffn2(
    const float* __restrict__ W2, const float* __restrict__ bf2,
    const float* __restrict__ g2, const float* __restrict__ be2,
    float* __restrict__ ws, float* __restrict__ out)
{
    const float* ff1 = ws + OFF_FF1;
    const float* upd = ws + OFF_UPD;
    __shared__ float As[32][33];
    __shared__ float Bs[32][128];
    const int tid = threadIdx.x;
    const int tx = tid & 31, ty = tid >> 5, ty4 = ty << 2;
    const int row0 = blockIdx.x * 32;
    float acc[4][4] = {};

    for (int k0 = 0; k0 < 256; k0 += 32) {
        #pragma unroll
        for (int l = 0; l < 4; l++) {
            int idx = tid + l * 256;
            int r = idx >> 5, c = idx & 31;
            int gr = row0 + r, gc = k0 + c;
            As[r][c] = (gr < N_NODES) ? ff1[gr * 256 + gc] : 0.f;
        }
        #pragma unroll
        for (int l = 0; l < 4; l++) {
            int idx = tid + l * 256;
            int r = idx >> 5, c = (idx & 31) << 2;
            *(float4*)&Bs[r][c] = *(const float4*)&W2[(k0 + r) * 128 + c];
        }
        __syncthreads();
        #pragma unroll
        for (int kk = 0; kk < 32; kk++) FMA16();
        __syncthreads();
    }
    float4 bb = *(const float4*)&bf2[tx << 2];
    float4 g4 = *(const float4*)&g2[tx << 2];
    float4 b4 = *(const float4*)&be2[tx << 2];
    #pragma unroll
    for (int r = 0; r < 4; r++) {
        int gr = row0 + ty4 + r;
        bool valid = gr < N_NODES;
        float4 t = {0.f, 0.f, 0.f, 0.f};
        if (valid) {
            float4 uv = *(const float4*)&upd[gr * 128 + (tx << 2)];
            t.x = acc[r][0] + bb.x + uv.x;
            t.y = acc[r][1] + bb.y + uv.y;
            t.z = acc[r][2] + bb.z + uv.z;
            t.w = acc[r][3] + bb.w + uv.w;
        }
        float s = t.x + t.y + t.z + t.w;
        s += __shfl_xor(s, 1); s += __shfl_xor(s, 2); s += __shfl_xor(s, 4);
        s += __shfl_xor(s, 8); s += __shfl_xor(s, 16);
        float mu = s * 0.0078125f;
        float dx = t.x - mu, dy = t.y - mu, dz = t.z - mu, dw = t.w - mu;
        float sq = dx * dx + dy * dy + dz * dz + dw * dw;
        sq += __shfl_xor(sq, 1); sq += __shfl_xor(sq, 2); sq += __shfl_xor(sq, 4);
        sq += __shfl_xor(sq, 8); sq += __shfl_xor(sq, 16);
        float rs = rsqrtf(sq * 0.0078125f + 1e-5f);
        if (valid) {
            float4 o;
            o.x = dx * rs * g4.x + b4.x;
            o.y = dy * rs * g4.y + b4.y;
            o.z = dz * rs * g4.z + b4.z;
            o.w = dw * rs * g4.w + b4.w;
            *(float4*)&out[gr * 128 + (tx << 2)] = o;
        }
    }
}

extern "C" void kernel_launch(void* const* d_in, const int* in_sizes, int n_in,
                              void* d_out, int out_size, void* d_ws, size_t ws_size,
                              hipStream_t stream)
{
    const float* ns  = (const float*)d_in[0];
    const float* nt  = (const float*)d_in[1];
    const int*   ei  = (const int*)d_in[2];
    const float* ee  = (const float*)d_in[3];
    const float* Wq  = (const float*)d_in[4];
    const float* bq  = (const float*)d_in[5];
    const float* Wk  = (const float*)d_in[6];
    const float* bk  = (const float*)d_in[7];
    const float* Wv  = (const float*)d_in[8];
    const float* bv  = (const float*)d_in[9];
    const float* Wo  = (const float*)d_in[10];
    const float* bo  = (const float*)d_in[11];
    const float* g1  = (const float*)d_in[12];
    const float* be1 = (const float*)d_in[13];
    const float* g2  = (const float*)d_in[14];
    const float* be2 = (const float*)d_in[15];
    const float* W1  = (const float*)d_in[16];
    const float* bf1 = (const float*)d_in[17];
    const float* W2  = (const float*)d_in[18];
    const float* bf2 = (const float*)d_in[19];
    float* ws  = (float*)d_ws;
    float* out = (float*)d_out;

    int* cnt  = (int*)(ws + OFF_CNT);
    int* offs = (int*)(ws + OFF_OFFS);
    int* srt  = (int*)(ws + OFF_SORT);

    const int nblk = (N_NODES + 31) / 32;

    // build CSR (counts zeroed each launch; ws is re-poisoned by harness)
    k_zero_int<<<(N_NODES + 255) / 256, 256, 0, stream>>>(cnt, N_NODES);
    k_hist<<<512, 256, 0, stream>>>(ei, cnt);
    k_scan<<<1, 1024, 0, stream>>>(cnt, offs);
    k_scatter<<<512, 256, 0, stream>>>(ei, cnt, srt);

    dim3 gq(nblk, 3);
    k_node_qkv<<<gq, 256, 0, stream>>>(ns, nt, Wq, bq, Wk, bk, Wv, bv, ws);

    // 1 wave per node: 50000 waves -> 12500 blocks of 256
    k_edge_csr<<<(N_NODES * 64 + 255) / 256, 256, 0, stream>>>(
        ei, ee, Wk + 160 * 128, Wv + 160 * 128, offs, srt, ws);

    k_out_ln1<<<nblk, 256, 0, stream>>>(ns, Wo, bo, g1, be1, ws);
    dim3 gf(nblk, 2);
    k_ffn1<<<gf, 256, 0, stream>>>(W1, bf1, ws);
    k_ffn2<<<nblk, 256, 0, stream>>>(W2, bf2, g2, be2, ws, out);
}